// Round 4
// baseline (410.225 us; speedup 1.0000x reference)
//
#include <hip/hip_runtime.h>
#include <stdint.h>

#define B_ 4
#define S_ 2048
#define D_ 512
#define H_ 8
#define FFN_ 2048
#define M_ (B_*S_)

typedef unsigned short u16;
typedef __attribute__((ext_vector_type(8))) __bf16 bf16x8;
typedef __attribute__((ext_vector_type(8))) u16 u16x8;
typedef __attribute__((ext_vector_type(4))) float f32x4;

__device__ __forceinline__ u16 f2bf(float f) {
  uint32_t u = __builtin_bit_cast(uint32_t, f);
  u += 0x7FFFu + ((u >> 16) & 1u);
  return (u16)(u >> 16);
}
__device__ __forceinline__ bf16x8 ldfrag(const u16* p) {
  return __builtin_bit_cast(bf16x8, *(const u16x8*)p);
}
__device__ __forceinline__ void gld16(const void* g, void* l) {
  __builtin_amdgcn_global_load_lds(
      (const __attribute__((address_space(1))) void*)g,
      (__attribute__((address_space(3))) void*)l, 16, 0, 0);
}

// ---------------- weight transpose to bf16: Wt[n][k] = bf16(W[k][n]) -------
__global__ __launch_bounds__(256)
void wtrans(const float* __restrict__ W, int K, int N, u16* __restrict__ Wt) {
  __shared__ float t[32][33];
  int n0 = blockIdx.x * 32, k0 = blockIdx.y * 32;
  int x = threadIdx.x, y = threadIdx.y;  // (32,8)
#pragma unroll
  for (int r = 0; r < 4; r++) t[y + 8*r][x] = W[(size_t)(k0 + y + 8*r) * N + n0 + x];
  __syncthreads();
#pragma unroll
  for (int r = 0; r < 4; r++) Wt[(size_t)(n0 + y + 8*r) * K + k0 + x] = f2bf(t[x][y + 8*r]);
}

__global__ void bcat(const float* __restrict__ bq, const float* __restrict__ bk,
                     const float* __restrict__ bv, float* __restrict__ o) {
  int i = blockIdx.x * 256 + threadIdx.x;
  o[i] = i < 512 ? bq[i] : (i < 1024 ? bk[i - 512] : bv[i - 1024]);
}

// ---------------- layernorm over rows of 512 ------------------------------
template <bool OUT32, bool OUT16>
__global__ __launch_bounds__(128)
void ln_k(const float* __restrict__ x, const float* __restrict__ g,
          const float* __restrict__ bta, float* __restrict__ y32, u16* __restrict__ y16) {
  int row = blockIdx.x;
  int t = threadIdx.x;
  const float* xr = x + (size_t)row * 512;
  f32x4 v = *(const f32x4*)(xr + t * 4);
  float s = v.x + v.y + v.z + v.w;
  float s2 = v.x*v.x + v.y*v.y + v.z*v.z + v.w*v.w;
#pragma unroll
  for (int m = 32; m; m >>= 1) { s += __shfl_xor(s, m); s2 += __shfl_xor(s2, m); }
  __shared__ float p[4];
  int wv = t >> 6;
  if ((t & 63) == 0) { p[wv] = s; p[2 + wv] = s2; }
  __syncthreads();
  s = p[0] + p[1]; s2 = p[2] + p[3];
  float mean = s * (1.f / 512.f);
  float var = s2 * (1.f / 512.f) - mean * mean;
  float rs = rsqrtf(var + 1e-5f);
#pragma unroll
  for (int j = 0; j < 4; j++) {
    float o = (v[j] - mean) * rs * g[t*4 + j] + bta[t*4 + j];
    if constexpr (OUT32) y32[(size_t)row * 512 + t*4 + j] = o;
    if constexpr (OUT16) y16[(size_t)row * 512 + t*4 + j] = f2bf(o);
  }
}

// ---------------- GEMM: C[M,N] = A[M,K](bf16) @ Wt[N,K]^T + bias ----------
// Register-fragment GEMM: NO LDS, NO barriers. Each wave loads its MFMA
// fragments global->VGPR directly (A[m][k] and Bt[n][k] are both fragment-
// layout: 16B/lane at (row+l15)*K + quad*8, wave = 16 rows x 64B coalesced).
// Register double-buffer + K-unroll x2 lets the compiler hide load latency
// with fine-grained vmcnt(N) under the MFMAs (no barrier = no vmcnt(0) drain).
// 1-D grid, XCD-aware raster keeps each A row-stripe in one XCD's L2.
template <int NTW, int NCOL, bool RESID, bool OUT32, bool OUT16>
__global__ __launch_bounds__(256)
void gemm_rf(const u16* __restrict__ A, const u16* __restrict__ Bt,
             const float* __restrict__ bias, int K, int N,
             const float* __restrict__ resid, float* __restrict__ C32,
             u16* __restrict__ C16) {
  const int tid = threadIdx.x;
  const int wave = tid >> 6, lane = tid & 63;
  const int l15 = lane & 15, quad = lane >> 4;
  const int wm = wave >> 1, wn = wave & 1;

  const int lin = blockIdx.x;
  const int rpx = (M_ / 128) / 8;              // row tiles per XCD
  const int xcd = lin & 7, local = lin >> 3;
  const int row0 = (xcd * rpx + local / NCOL) * 128;
  const int col0 = (local % NCOL) * (NTW * 32);

  const u16* aP[4];
#pragma unroll
  for (int mt = 0; mt < 4; mt++)
    aP[mt] = A + (size_t)(row0 + wm * 64 + mt * 16 + l15) * K + quad * 8;
  const u16* bP[NTW];
#pragma unroll
  for (int nt = 0; nt < NTW; nt++)
    bP[nt] = Bt + (size_t)(col0 + wn * (NTW * 16) + nt * 16 + l15) * K + quad * 8;

  f32x4 acc[4][NTW];
#pragma unroll
  for (int i = 0; i < 4; i++)
#pragma unroll
    for (int j = 0; j < NTW; j++) acc[i][j] = (f32x4){0.f, 0.f, 0.f, 0.f};

  bf16x8 a0[4], b0[NTW], a1[4], b1[NTW];
#pragma unroll
  for (int mt = 0; mt < 4; mt++) a0[mt] = ldfrag(aP[mt]);
#pragma unroll
  for (int nt = 0; nt < NTW; nt++) b0[nt] = ldfrag(bP[nt]);

  for (int k0 = 0; k0 + 64 < K; k0 += 64) {
#pragma unroll
    for (int mt = 0; mt < 4; mt++) a1[mt] = ldfrag(aP[mt] + k0 + 32);
#pragma unroll
    for (int nt = 0; nt < NTW; nt++) b1[nt] = ldfrag(bP[nt] + k0 + 32);
#pragma unroll
    for (int mt = 0; mt < 4; mt++)
#pragma unroll
      for (int nt = 0; nt < NTW; nt++)
        acc[mt][nt] = __builtin_amdgcn_mfma_f32_16x16x32_bf16(a0[mt], b0[nt], acc[mt][nt], 0, 0, 0);
#pragma unroll
    for (int mt = 0; mt < 4; mt++) a0[mt] = ldfrag(aP[mt] + k0 + 64);
#pragma unroll
    for (int nt = 0; nt < NTW; nt++) b0[nt] = ldfrag(bP[nt] + k0 + 64);
#pragma unroll
    for (int mt = 0; mt < 4; mt++)
#pragma unroll
      for (int nt = 0; nt < NTW; nt++)
        acc[mt][nt] = __builtin_amdgcn_mfma_f32_16x16x32_bf16(a1[mt], b1[nt], acc[mt][nt], 0, 0, 0);
  }
  // K % 64 == 0: one pair remains (tiles K-64 in a0/b0, K-32 loaded here)
#pragma unroll
  for (int mt = 0; mt < 4; mt++) a1[mt] = ldfrag(aP[mt] + K - 32);
#pragma unroll
  for (int nt = 0; nt < NTW; nt++) b1[nt] = ldfrag(bP[nt] + K - 32);
#pragma unroll
  for (int mt = 0; mt < 4; mt++)
#pragma unroll
    for (int nt = 0; nt < NTW; nt++)
      acc[mt][nt] = __builtin_amdgcn_mfma_f32_16x16x32_bf16(a0[mt], b0[nt], acc[mt][nt], 0, 0, 0);
#pragma unroll
  for (int mt = 0; mt < 4; mt++)
#pragma unroll
    for (int nt = 0; nt < NTW; nt++)
      acc[mt][nt] = __builtin_amdgcn_mfma_f32_16x16x32_bf16(a1[mt], b1[nt], acc[mt][nt], 0, 0, 0);

#pragma unroll
  for (int mt = 0; mt < 4; mt++)
#pragma unroll
    for (int nt = 0; nt < NTW; nt++) {
      int n = col0 + wn * (NTW * 16) + nt * 16 + l15;
      float bv = bias[n];
#pragma unroll
      for (int r = 0; r < 4; r++) {
        int m = row0 + wm * 64 + mt * 16 + quad * 4 + r;
        float val = acc[mt][nt][r] + bv;
        if constexpr (RESID) val += resid[(size_t)m * N + n];
        if constexpr (OUT32) C32[(size_t)m * N + n] = val;
        if constexpr (OUT16) C16[(size_t)m * N + n] = f2bf(val);
      }
    }
}

// ---------------- transpose V head-wise: vt[b,h,d,s] ----------------------
__global__ __launch_bounds__(256)
void vtrans(const u16* __restrict__ qkv, u16* __restrict__ vt) {
  __shared__ u16 t[64][65];
  int s0 = blockIdx.x * 64, h = blockIdx.y, b = blockIdx.z;
  int x = threadIdx.x, y = threadIdx.y;  // (64,4)
  const u16* src = qkv + (size_t)(b * 2048 + s0) * 1536 + 1024 + h * 64;
#pragma unroll
  for (int r = 0; r < 16; r++) { int s = y + 4*r; t[s][x] = src[(size_t)s * 1536 + x]; }
  __syncthreads();
  u16* dst = vt + (size_t)((b * 8 + h) * 64) * 2048 + s0;
#pragma unroll
  for (int r = 0; r < 16; r++) { int d = y + 4*r; dst[(size_t)d * 2048 + x] = t[x][d]; }
}

// ---------------- attention: block = (b, h, 128 q-rows) -------------------
// Ks: 128x64 u16 (granule c of row r at c^(r&7));  Vts: 64x128 u16
// (granule c at (c&8)|((c&7)^(d&7)));  Ps: 128xPSTR unswizzled; Qs aliases Ps.
#define PSTR 136
__global__ __launch_bounds__(256)
void attn_k(const u16* __restrict__ qkv, const u16* __restrict__ vt,
            const float* __restrict__ hres, float* __restrict__ attn) {
  __shared__ __align__(16) u16 smem[8192 + 8192 + 128 * PSTR];
  u16* Ks = smem;
  u16* Vts = smem + 8192;
  u16* Ps = smem + 16384;
  u16* Qs = Ps;

  const int c = blockIdx.x, hh = blockIdx.y, b = blockIdx.z;
  const int s0 = c * 128;
  const int tid = threadIdx.x, wave = tid >> 6, lane = tid & 63;
  const int l15 = lane & 15, quad = lane >> 4;
  const int t_lo = (c > 4) ? c - 4 : 0;
  const int t_hi = (c + 2 < 16) ? c + 2 : 16;
  const int l7sw = l15 & 7;

  // stage Q (128x64), swizzled
  {
    const int cg = ((lane & 7) ^ (lane >> 3)) * 8;
    const int cp = (lane & 7) * 8;
#pragma unroll
    for (int q2 = 0; q2 < 4; q2++) {
      int r = wave * 32 + q2 * 8 + (lane >> 3);
      gld16(qkv + (size_t)(b * 2048 + s0 + r) * 1536 + hh * 64 + cg, Qs + r * 64 + cp);
    }
  }
  __syncthreads();
  bf16x8 qf[2][2];
#pragma unroll
  for (int qg = 0; qg < 2; qg++)
#pragma unroll
    for (int f = 0; f < 2; f++)
      qf[qg][f] = ldfrag(Qs + (qg * 64 + wave * 16 + l15) * 64 + (((f * 4 + quad) ^ l7sw) * 8));

  f32x4 accO[2][4];
#pragma unroll
  for (int qg = 0; qg < 2; qg++)
#pragma unroll
    for (int i = 0; i < 4; i++) accO[qg][i] = (f32x4){0.f, 0.f, 0.f, 0.f};
  float den[2][4] = {{0.f, 0.f, 0.f, 0.f}, {0.f, 0.f, 0.f, 0.f}};

  for (int kt = t_lo; kt < t_hi; ++kt) {
    __syncthreads();  // prior-iter reads done before restage
    {
      const int cgk = ((lane & 7) ^ (lane >> 3)) * 8;
      const int cpk = (lane & 7) * 8;
#pragma unroll
      for (int q2 = 0; q2 < 4; q2++) {  // K tile 128 rows
        int r = wave * 32 + q2 * 8 + (lane >> 3);
        gld16(qkv + (size_t)(b * 2048 + kt * 128 + r) * 1536 + 512 + hh * 64 + cgk,
              Ks + r * 64 + cpk);
      }
      const int cpv = (lane & 15) * 8;
#pragma unroll
      for (int q2 = 0; q2 < 4; q2++) {  // Vt tile 64 rows
        int d = (wave * 4 + q2) * 4 + (lane >> 4);
        int cgv = ((lane & 8) | ((lane & 7) ^ (lane >> 4) ^ ((q2 & 1) << 2))) * 8;
        gld16(vt + (size_t)((b * 8 + hh) * 64 + d) * 2048 + kt * 128 + cgv,
              Vts + d * 128 + cpv);
      }
    }
    __syncthreads();

#pragma unroll
    for (int nt = 0; nt < 8; nt++) {
      bf16x8 kf0 = ldfrag(Ks + (nt * 16 + l15) * 64 + ((quad ^ l7sw) * 8));
      bf16x8 kf1 = ldfrag(Ks + (nt * 16 + l15) * 64 + (((4 + quad) ^ l7sw) * 8));
#pragma unroll
      for (int qg = 0; qg < 2; qg++) {
        f32x4 s4 = (f32x4){0.f, 0.f, 0.f, 0.f};
        s4 = __builtin_amdgcn_mfma_f32_16x16x32_bf16(qf[qg][0], kf0, s4, 0, 0, 0);
        s4 = __builtin_amdgcn_mfma_f32_16x16x32_bf16(qf[qg][1], kf1, s4, 0, 0, 0);
#pragma unroll
        for (int r = 0; r < 4; r++) {
          float pp = exp2f(s4[r] * (1.4426950408889634f * 0.125f));  // exp(s/8)
          den[qg][r] += pp;
          Ps[(qg * 64 + wave * 16 + quad * 4 + r) * PSTR + nt * 16 + l15] = f2bf(pp);
        }
      }
    }
    // PV — wave reads only its own P rows, no cross-wave barrier needed
#pragma unroll
    for (int ki = 0; ki < 4; ki++) {
      bf16x8 pf[2];
#pragma unroll
      for (int qg = 0; qg < 2; qg++)
        pf[qg] = ldfrag(Ps + (qg * 64 + wave * 16 + l15) * PSTR + (ki * 4 + quad) * 8);
#pragma unroll
      for (int dt = 0; dt < 4; dt++) {
        int g = ki * 4 + quad;
        bf16x8 vf = ldfrag(Vts + (dt * 16 + l15) * 128 + (((g & 8) | ((g & 7) ^ l7sw)) * 8));
#pragma unroll
        for (int qg = 0; qg < 2; qg++)
          accO[qg][dt] = __builtin_amdgcn_mfma_f32_16x16x32_bf16(pf[qg], vf, accO[qg][dt], 0, 0, 0);
      }
    }
  }
  // reduce den across the 16-lane col group
#pragma unroll
  for (int qg = 0; qg < 2; qg++)
#pragma unroll
    for (int r = 0; r < 4; r++) {
      float d = den[qg][r];
      d += __shfl_xor(d, 1); d += __shfl_xor(d, 2);
      d += __shfl_xor(d, 4); d += __shfl_xor(d, 8);
      den[qg][r] = d;
    }
#pragma unroll
  for (int qg = 0; qg < 2; qg++)
#pragma unroll
    for (int dt = 0; dt < 4; dt++)
#pragma unroll
      for (int r = 0; r < 4; r++) {
        int m = s0 + qg * 64 + wave * 16 + quad * 4 + r;
        size_t idx = (size_t)(b * 2048 + m) * 512 + hh * 64 + dt * 16 + l15;
        attn[idx] = accO[qg][dt][r] / den[qg][r] + hres[idx];
      }
}

extern "C" void kernel_launch(void* const* d_in, const int* in_sizes, int n_in,
                              void* d_out, int out_size, void* d_ws, size_t ws_size,
                              hipStream_t stream) {
  (void)in_sizes; (void)n_in; (void)out_size; (void)ws_size;
  const float* x       = (const float*)d_in[0];
  const float* ln_in_g = (const float*)d_in[2];
  const float* ln_in_b = (const float*)d_in[3];
  const float* wq = (const float*)d_in[4];
  const float* bq = (const float*)d_in[5];
  const float* wk = (const float*)d_in[6];
  const float* bk = (const float*)d_in[7];
  const float* wv = (const float*)d_in[8];
  const float* bv = (const float*)d_in[9];
  const float* ln1_g = (const float*)d_in[10];
  const float* ln1_b = (const float*)d_in[11];
  const float* w1 = (const float*)d_in[12];
  const float* b1 = (const float*)d_in[13];
  const float* w2 = (const float*)d_in[14];
  const float* b2 = (const float*)d_in[15];
  const float* ln2_g = (const float*)d_in[16];
  const float* ln2_b = (const float*)d_in[17];

  char* ws = (char*)d_ws;
  size_t off = 0;
  auto alloc = [&](size_t bytes) {
    void* p = ws + off;
    off = (off + bytes + 255) & ~(size_t)255;
    return p;
  };
  u16*   wqkvt = (u16*)  alloc((size_t)1536 * 512 * 2);
  float* bqkv  = (float*)alloc(1536 * 4);
  u16*   w1t   = (u16*)  alloc((size_t)2048 * 512 * 2);
  u16*   w2t   = (u16*)  alloc((size_t)512 * 2048 * 2);
  float* h32   = (float*)alloc((size_t)M_ * 512 * 4);   // later reused as out2
  u16*   h16   = (u16*)  alloc((size_t)M_ * 512 * 2);   // later reused as o16
  u16*   qkv16 = (u16*)  alloc((size_t)M_ * 1536 * 2);  // + vt below = ffn-mid alias
  u16*   vtb   = (u16*)  alloc((size_t)B_ * H_ * 64 * 2048 * 2);
  float* attn32= (float*)alloc((size_t)M_ * 512 * 4);
  float* out2  = h32;
  u16*   o16   = h16;
  u16*   f16b  = qkv16;  // 8192*2048*2 bytes spans qkv16+vtb exactly

  wtrans<<<dim3(16, 16), dim3(32, 8), 0, stream>>>(wq, 512, 512, wqkvt);
  wtrans<<<dim3(16, 16), dim3(32, 8), 0, stream>>>(wk, 512, 512, wqkvt + (size_t)512 * 512);
  wtrans<<<dim3(16, 16), dim3(32, 8), 0, stream>>>(wv, 512, 512, wqkvt + (size_t)1024 * 512);
  wtrans<<<dim3(64, 16), dim3(32, 8), 0, stream>>>(w1, 512, 2048, w1t);
  wtrans<<<dim3(16, 64), dim3(32, 8), 0, stream>>>(w2, 2048, 512, w2t);
  bcat<<<6, 256, 0, stream>>>(bq, bk, bv, bqkv);

  ln_k<true, true><<<M_, 128, 0, stream>>>(x, ln_in_g, ln_in_b, h32, h16);
  gemm_rf<4, 12, false, false, true><<<dim3(12 * 64), 256, 0, stream>>>(
      h16, wqkvt, bqkv, 512, 1536, nullptr, nullptr, qkv16);
  vtrans<<<dim3(32, 8, 4), dim3(64, 4), 0, stream>>>(qkv16, vtb);
  attn_k<<<dim3(16, 8, 4), 256, 0, stream>>>(qkv16, vtb, h32, attn32);
  ln_k<false, true><<<M_, 128, 0, stream>>>(attn32, ln1_g, ln1_b, nullptr, o16);
  gemm_rf<4, 16, false, false, true><<<dim3(16 * 64), 256, 0, stream>>>(
      o16, w1t, b1, 512, 2048, nullptr, nullptr, f16b);
  gemm_rf<2, 8, true, true, false><<<dim3(8 * 64), 256, 0, stream>>>(
      f16b, w2t, b2, 2048, 512, attn32, out2, nullptr);
  ln_k<true, false><<<M_, 128, 0, stream>>>(out2, ln2_g, ln2_b, (float*)d_out, nullptr);
}

// Round 5
// 296.176 us; speedup vs baseline: 1.3851x; 1.3851x over previous
//
#include <hip/hip_runtime.h>
#include <stdint.h>

#define B_ 4
#define S_ 2048
#define D_ 512
#define H_ 8
#define FFN_ 2048
#define M_ (B_*S_)

typedef unsigned short u16;
typedef __attribute__((ext_vector_type(8))) __bf16 bf16x8;
typedef __attribute__((ext_vector_type(8))) u16 u16x8;
typedef __attribute__((ext_vector_type(4))) float f32x4;

__device__ __forceinline__ u16 f2bf(float f) {
  uint32_t u = __builtin_bit_cast(uint32_t, f);
  u += 0x7FFFu + ((u >> 16) & 1u);
  return (u16)(u >> 16);
}
__device__ __forceinline__ bf16x8 ldfrag(const u16* p) {
  return __builtin_bit_cast(bf16x8, *(const u16x8*)p);
}
__device__ __forceinline__ void gld16(const void* g, void* l) {
  __builtin_amdgcn_global_load_lds(
      (const __attribute__((address_space(1))) void*)g,
      (__attribute__((address_space(3))) void*)l, 16, 0, 0);
}

// ---------------- weight transpose to bf16: Wt[n][k] = bf16(W[k][n]) -------
__global__ __launch_bounds__(256)
void wtrans(const float* __restrict__ W, int K, int N, u16* __restrict__ Wt) {
  __shared__ float t[32][33];
  int n0 = blockIdx.x * 32, k0 = blockIdx.y * 32;
  int x = threadIdx.x, y = threadIdx.y;  // (32,8)
#pragma unroll
  for (int r = 0; r < 4; r++) t[y + 8*r][x] = W[(size_t)(k0 + y + 8*r) * N + n0 + x];
  __syncthreads();
#pragma unroll
  for (int r = 0; r < 4; r++) Wt[(size_t)(n0 + y + 8*r) * K + k0 + x] = f2bf(t[x][y + 8*r]);
}

__global__ void bcat(const float* __restrict__ bq, const float* __restrict__ bk,
                     const float* __restrict__ bv, float* __restrict__ o) {
  int i = blockIdx.x * 256 + threadIdx.x;
  o[i] = i < 512 ? bq[i] : (i < 1024 ? bk[i - 512] : bv[i - 1024]);
}

// ---------------- layernorm over rows of 512 ------------------------------
template <bool OUT32, bool OUT16>
__global__ __launch_bounds__(128)
void ln_k(const float* __restrict__ x, const float* __restrict__ g,
          const float* __restrict__ bta, float* __restrict__ y32, u16* __restrict__ y16) {
  int row = blockIdx.x;
  int t = threadIdx.x;
  const float* xr = x + (size_t)row * 512;
  f32x4 v = *(const f32x4*)(xr + t * 4);
  float s = v.x + v.y + v.z + v.w;
  float s2 = v.x*v.x + v.y*v.y + v.z*v.z + v.w*v.w;
#pragma unroll
  for (int m = 32; m; m >>= 1) { s += __shfl_xor(s, m); s2 += __shfl_xor(s2, m); }
  __shared__ float p[4];
  int wv = t >> 6;
  if ((t & 63) == 0) { p[wv] = s; p[2 + wv] = s2; }
  __syncthreads();
  s = p[0] + p[1]; s2 = p[2] + p[3];
  float mean = s * (1.f / 512.f);
  float var = s2 * (1.f / 512.f) - mean * mean;
  float rs = rsqrtf(var + 1e-5f);
#pragma unroll
  for (int j = 0; j < 4; j++) {
    float o = (v[j] - mean) * rs * g[t*4 + j] + bta[t*4 + j];
    if constexpr (OUT32) y32[(size_t)row * 512 + t*4 + j] = o;
    if constexpr (OUT16) y16[(size_t)row * 512 + t*4 + j] = f2bf(o);
  }
}

// ---------------- GEMM: C[M,N] = A[M,K](bf16) @ Wt[N,K]^T + bias ----------
// LDS-staged, DOUBLE-BUFFERED single-barrier K-loop: iter i issues
// global_load_lds for tile i+1 into buf (i^1), then ds_read+MFMA tile i from
// buf (i&1). The barrier's vmcnt(0) drain waits on loads issued one full
// iteration ago (covered by 16 MFMAs + 8 ds_read_b128), not 2 instrs ago.
// LDS swizzle: granule c of row r stored at c ^ ((r>>1)&3).
// 1-D grid, XCD-aware raster keeps each A row-stripe in one XCD's L2.
template <int NTW, int NCOL, bool RESID, bool OUT32, bool OUT16>
__global__ __launch_bounds__(256)
void gemm_db(const u16* __restrict__ A, const u16* __restrict__ Bt,
             const float* __restrict__ bias, int K, int N,
             const float* __restrict__ resid, float* __restrict__ C32,
             u16* __restrict__ C16) {
  __shared__ __align__(16) u16 As[2][128 * 32];
  __shared__ __align__(16) u16 Bs[2][NTW * 1024];
  const int tid = threadIdx.x;
  const int wave = tid >> 6, lane = tid & 63;
  const int l15 = lane & 15, quad = lane >> 4;
  const int wm = wave >> 1, wn = wave & 1;

  const int lin = blockIdx.x;
  const int rpx = (M_ / 128) / 8;              // row tiles per XCD
  const int xcd = lin & 7, local = lin >> 3;
  const int row0 = (xcd * rpx + local / NCOL) * 128;
  const int col0 = (local % NCOL) * (NTW * 32);

  f32x4 acc[4][NTW];
#pragma unroll
  for (int i = 0; i < 4; i++)
#pragma unroll
    for (int j = 0; j < NTW; j++) acc[i][j] = (f32x4){0.f, 0.f, 0.f, 0.f};

  const int lr = lane >> 2;
  const int lc = ((lane & 3) ^ ((lane >> 3) & 3)) * 8;  // swizzled source granule
  const u16* aG0 = A + (size_t)(row0 + (wave * 2) * 16 + lr) * K + lc;
  const u16* aG1 = A + (size_t)(row0 + (wave * 2 + 1) * 16 + lr) * K + lc;
  const int aO0 = (wave * 2) * 512 + lane * 8;
  const int aO1 = (wave * 2 + 1) * 512 + lane * 8;
  const u16* bG[NTW / 2];
  int bO[NTW / 2];
#pragma unroll
  for (int i = 0; i < NTW / 2; i++) {
    int ch = wave * (NTW / 2) + i;
    bG[i] = Bt + (size_t)(col0 + ch * 16 + lr) * K + lc;
    bO[i] = ch * 512 + lane * 8;
  }
  const int rsw = (l15 >> 1) & 3;  // frag-read swizzle term

  // preload tile 0 into buf 0
  gld16(aG0, &As[0][aO0]);
  gld16(aG1, &As[0][aO1]);
#pragma unroll
  for (int i = 0; i < NTW / 2; i++) gld16(bG[i], &Bs[0][bO[i]]);

  const int nIter = K >> 5;
  for (int it = 0; it < nIter; it++) {
    __syncthreads();  // drains buf[cur] loads (issued last iter) + prior reads of buf[nxt]
    const int cur = it & 1;
    if (it + 1 < nIter) {
      const int nxt = cur ^ 1;
      const int k = (it + 1) << 5;
      gld16(aG0 + k, &As[nxt][aO0]);
      gld16(aG1 + k, &As[nxt][aO1]);
#pragma unroll
      for (int i = 0; i < NTW / 2; i++) gld16(bG[i] + k, &Bs[nxt][bO[i]]);
    }
    bf16x8 af[4], bf[NTW];
#pragma unroll
    for (int mt = 0; mt < 4; mt++)
      af[mt] = ldfrag(&As[cur][(wm * 64 + mt * 16 + l15) * 32 + ((quad ^ rsw) * 8)]);
#pragma unroll
    for (int nt = 0; nt < NTW; nt++)
      bf[nt] = ldfrag(&Bs[cur][(wn * (NTW * 16) + nt * 16 + l15) * 32 + ((quad ^ rsw) * 8)]);
#pragma unroll
    for (int mt = 0; mt < 4; mt++)
#pragma unroll
      for (int nt = 0; nt < NTW; nt++)
        acc[mt][nt] = __builtin_amdgcn_mfma_f32_16x16x32_bf16(af[mt], bf[nt], acc[mt][nt], 0, 0, 0);
  }
#pragma unroll
  for (int mt = 0; mt < 4; mt++)
#pragma unroll
    for (int nt = 0; nt < NTW; nt++) {
      int n = col0 + wn * (NTW * 16) + nt * 16 + l15;
      float bv = bias[n];
#pragma unroll
      for (int r = 0; r < 4; r++) {
        int m = row0 + wm * 64 + mt * 16 + quad * 4 + r;
        float val = acc[mt][nt][r] + bv;
        if constexpr (RESID) val += resid[(size_t)m * N + n];
        if constexpr (OUT32) C32[(size_t)m * N + n] = val;
        if constexpr (OUT16) C16[(size_t)m * N + n] = f2bf(val);
      }
    }
}

// ---------------- transpose V head-wise: vt[b,h,d,s] ----------------------
__global__ __launch_bounds__(256)
void vtrans(const u16* __restrict__ qkv, u16* __restrict__ vt) {
  __shared__ u16 t[64][65];
  int s0 = blockIdx.x * 64, h = blockIdx.y, b = blockIdx.z;
  int x = threadIdx.x, y = threadIdx.y;  // (64,4)
  const u16* src = qkv + (size_t)(b * 2048 + s0) * 1536 + 1024 + h * 64;
#pragma unroll
  for (int r = 0; r < 16; r++) { int s = y + 4*r; t[s][x] = src[(size_t)s * 1536 + x]; }
  __syncthreads();
  u16* dst = vt + (size_t)((b * 8 + h) * 64) * 2048 + s0;
#pragma unroll
  for (int r = 0; r < 16; r++) { int d = y + 4*r; dst[(size_t)d * 2048 + x] = t[x][d]; }
}

// ---------------- attention: block = (b, h, 128 q-rows) -------------------
// Ks: 128x64 u16 (granule c of row r at c^(r&7));  Vts: 64x128 u16
// (granule c at (c&8)|((c&7)^(d&7)));  Ps: 128xPSTR unswizzled; Qs aliases Ps.
#define PSTR 136
__global__ __launch_bounds__(256)
void attn_k(const u16* __restrict__ qkv, const u16* __restrict__ vt,
            const float* __restrict__ hres, float* __restrict__ attn) {
  __shared__ __align__(16) u16 smem[8192 + 8192 + 128 * PSTR];
  u16* Ks = smem;
  u16* Vts = smem + 8192;
  u16* Ps = smem + 16384;
  u16* Qs = Ps;

  const int c = blockIdx.x, hh = blockIdx.y, b = blockIdx.z;
  const int s0 = c * 128;
  const int tid = threadIdx.x, wave = tid >> 6, lane = tid & 63;
  const int l15 = lane & 15, quad = lane >> 4;
  const int t_lo = (c > 4) ? c - 4 : 0;
  const int t_hi = (c + 2 < 16) ? c + 2 : 16;
  const int l7sw = l15 & 7;

  // stage Q (128x64), swizzled
  {
    const int cg = ((lane & 7) ^ (lane >> 3)) * 8;
    const int cp = (lane & 7) * 8;
#pragma unroll
    for (int q2 = 0; q2 < 4; q2++) {
      int r = wave * 32 + q2 * 8 + (lane >> 3);
      gld16(qkv + (size_t)(b * 2048 + s0 + r) * 1536 + hh * 64 + cg, Qs + r * 64 + cp);
    }
  }
  __syncthreads();
  bf16x8 qf[2][2];
#pragma unroll
  for (int qg = 0; qg < 2; qg++)
#pragma unroll
    for (int f = 0; f < 2; f++)
      qf[qg][f] = ldfrag(Qs + (qg * 64 + wave * 16 + l15) * 64 + (((f * 4 + quad) ^ l7sw) * 8));

  f32x4 accO[2][4];
#pragma unroll
  for (int qg = 0; qg < 2; qg++)
#pragma unroll
    for (int i = 0; i < 4; i++) accO[qg][i] = (f32x4){0.f, 0.f, 0.f, 0.f};
  float den[2][4] = {{0.f, 0.f, 0.f, 0.f}, {0.f, 0.f, 0.f, 0.f}};

  for (int kt = t_lo; kt < t_hi; ++kt) {
    __syncthreads();  // prior-iter reads done before restage
    {
      const int cgk = ((lane & 7) ^ (lane >> 3)) * 8;
      const int cpk = (lane & 7) * 8;
#pragma unroll
      for (int q2 = 0; q2 < 4; q2++) {  // K tile 128 rows
        int r = wave * 32 + q2 * 8 + (lane >> 3);
        gld16(qkv + (size_t)(b * 2048 + kt * 128 + r) * 1536 + 512 + hh * 64 + cgk,
              Ks + r * 64 + cpk);
      }
      const int cpv = (lane & 15) * 8;
#pragma unroll
      for (int q2 = 0; q2 < 4; q2++) {  // Vt tile 64 rows
        int d = (wave * 4 + q2) * 4 + (lane >> 4);
        int cgv = ((lane & 8) | ((lane & 7) ^ (lane >> 4) ^ ((q2 & 1) << 2))) * 8;
        gld16(vt + (size_t)((b * 8 + hh) * 64 + d) * 2048 + kt * 128 + cgv,
              Vts + d * 128 + cpv);
      }
    }
    __syncthreads();

#pragma unroll
    for (int nt = 0; nt < 8; nt++) {
      bf16x8 kf0 = ldfrag(Ks + (nt * 16 + l15) * 64 + ((quad ^ l7sw) * 8));
      bf16x8 kf1 = ldfrag(Ks + (nt * 16 + l15) * 64 + (((4 + quad) ^ l7sw) * 8));
#pragma unroll
      for (int qg = 0; qg < 2; qg++) {
        f32x4 s4 = (f32x4){0.f, 0.f, 0.f, 0.f};
        s4 = __builtin_amdgcn_mfma_f32_16x16x32_bf16(qf[qg][0], kf0, s4, 0, 0, 0);
        s4 = __builtin_amdgcn_mfma_f32_16x16x32_bf16(qf[qg][1], kf1, s4, 0, 0, 0);
#pragma unroll
        for (int r = 0; r < 4; r++) {
          float pp = exp2f(s4[r] * (1.4426950408889634f * 0.125f));  // exp(s/8)
          den[qg][r] += pp;
          Ps[(qg * 64 + wave * 16 + quad * 4 + r) * PSTR + nt * 16 + l15] = f2bf(pp);
        }
      }
    }
    // PV — wave reads only its own P rows, no cross-wave barrier needed
#pragma unroll
    for (int ki = 0; ki < 4; ki++) {
      bf16x8 pf[2];
#pragma unroll
      for (int qg = 0; qg < 2; qg++)
        pf[qg] = ldfrag(Ps + (qg * 64 + wave * 16 + l15) * PSTR + (ki * 4 + quad) * 8);
#pragma unroll
      for (int dt = 0; dt < 4; dt++) {
        int g = ki * 4 + quad;
        bf16x8 vf = ldfrag(Vts + (dt * 16 + l15) * 128 + (((g & 8) | ((g & 7) ^ l7sw)) * 8));
#pragma unroll
        for (int qg = 0; qg < 2; qg++)
          accO[qg][dt] = __builtin_amdgcn_mfma_f32_16x16x32_bf16(pf[qg], vf, accO[qg][dt], 0, 0, 0);
      }
    }
  }
  // reduce den across the 16-lane col group
#pragma unroll
  for (int qg = 0; qg < 2; qg++)
#pragma unroll
    for (int r = 0; r < 4; r++) {
      float d = den[qg][r];
      d += __shfl_xor(d, 1); d += __shfl_xor(d, 2);
      d += __shfl_xor(d, 4); d += __shfl_xor(d, 8);
      den[qg][r] = d;
    }
#pragma unroll
  for (int qg = 0; qg < 2; qg++)
#pragma unroll
    for (int dt = 0; dt < 4; dt++)
#pragma unroll
      for (int r = 0; r < 4; r++) {
        int m = s0 + qg * 64 + wave * 16 + quad * 4 + r;
        size_t idx = (size_t)(b * 2048 + m) * 512 + hh * 64 + dt * 16 + l15;
        attn[idx] = accO[qg][dt][r] / den[qg][r] + hres[idx];
      }
}

extern "C" void kernel_launch(void* const* d_in, const int* in_sizes, int n_in,
                              void* d_out, int out_size, void* d_ws, size_t ws_size,
                              hipStream_t stream) {
  (void)in_sizes; (void)n_in; (void)out_size; (void)ws_size;
  const float* x       = (const float*)d_in[0];
  const float* ln_in_g = (const float*)d_in[2];
  const float* ln_in_b = (const float*)d_in[3];
  const float* wq = (const float*)d_in[4];
  const float* bq = (const float*)d_in[5];
  const float* wk = (const float*)d_in[6];
  const float* bk = (const float*)d_in[7];
  const float* wv = (const float*)d_in[8];
  const float* bv = (const float*)d_in[9];
  const float* ln1_g = (const float*)d_in[10];
  const float* ln1_b = (const float*)d_in[11];
  const float* w1 = (const float*)d_in[12];
  const float* b1 = (const float*)d_in[13];
  const float* w2 = (const float*)d_in[14];
  const float* b2 = (const float*)d_in[15];
  const float* ln2_g = (const float*)d_in[16];
  const float* ln2_b = (const float*)d_in[17];

  char* ws = (char*)d_ws;
  size_t off = 0;
  auto alloc = [&](size_t bytes) {
    void* p = ws + off;
    off = (off + bytes + 255) & ~(size_t)255;
    return p;
  };
  u16*   wqkvt = (u16*)  alloc((size_t)1536 * 512 * 2);
  float* bqkv  = (float*)alloc(1536 * 4);
  u16*   w1t   = (u16*)  alloc((size_t)2048 * 512 * 2);
  u16*   w2t   = (u16*)  alloc((size_t)512 * 2048 * 2);
  float* h32   = (float*)alloc((size_t)M_ * 512 * 4);   // later reused as out2
  u16*   h16   = (u16*)  alloc((size_t)M_ * 512 * 2);   // later reused as o16
  u16*   qkv16 = (u16*)  alloc((size_t)M_ * 1536 * 2);  // + vt below = ffn-mid alias
  u16*   vtb   = (u16*)  alloc((size_t)B_ * H_ * 64 * 2048 * 2);
  float* attn32= (float*)alloc((size_t)M_ * 512 * 4);
  float* out2  = h32;
  u16*   o16   = h16;
  u16*   f16b  = qkv16;  // 8192*2048*2 bytes spans qkv16+vtb exactly

  wtrans<<<dim3(16, 16), dim3(32, 8), 0, stream>>>(wq, 512, 512, wqkvt);
  wtrans<<<dim3(16, 16), dim3(32, 8), 0, stream>>>(wk, 512, 512, wqkvt + (size_t)512 * 512);
  wtrans<<<dim3(16, 16), dim3(32, 8), 0, stream>>>(wv, 512, 512, wqkvt + (size_t)1024 * 512);
  wtrans<<<dim3(64, 16), dim3(32, 8), 0, stream>>>(w1, 512, 2048, w1t);
  wtrans<<<dim3(16, 64), dim3(32, 8), 0, stream>>>(w2, 2048, 512, w2t);
  bcat<<<6, 256, 0, stream>>>(bq, bk, bv, bqkv);

  ln_k<true, true><<<M_, 128, 0, stream>>>(x, ln_in_g, ln_in_b, h32, h16);
  gemm_db<4, 12, false, false, true><<<dim3(12 * 64), 256, 0, stream>>>(
      h16, wqkvt, bqkv, 512, 1536, nullptr, nullptr, qkv16);
  vtrans<<<dim3(32, 8, 4), dim3(64, 4), 0, stream>>>(qkv16, vtb);
  attn_k<<<dim3(16, 8, 4), 256, 0, stream>>>(qkv16, vtb, h32, attn32);
  ln_k<false, true><<<M_, 128, 0, stream>>>(attn32, ln1_g, ln1_b, nullptr, o16);
  gemm_db<4, 16, false, false, true><<<dim3(16 * 64), 256, 0, stream>>>(
      o16, w1t, b1, 512, 2048, nullptr, nullptr, f16b);
  gemm_db<2, 8, true, true, false><<<dim3(8 * 64), 256, 0, stream>>>(
      f16b, w2t, b2, 2048, 512, attn32, out2, nullptr);
  ln_k<true, false><<<M_, 128, 0, stream>>>(out2, ln2_g, ln2_b, (float*)d_out, nullptr);
}

// Round 6
// 296.161 us; speedup vs baseline: 1.3851x; 1.0000x over previous
//
#include <hip/hip_runtime.h>
#include <stdint.h>

#define B_ 4
#define S_ 2048
#define D_ 512
#define H_ 8
#define FFN_ 2048
#define M_ (B_*S_)

typedef unsigned short u16;
typedef __attribute__((ext_vector_type(8))) __bf16 bf16x8;
typedef __attribute__((ext_vector_type(8))) u16 u16x8;
typedef __attribute__((ext_vector_type(4))) u16 u16x4;
typedef __attribute__((ext_vector_type(4))) float f32x4;

__device__ __forceinline__ u16 f2bf(float f) {
  uint32_t u = __builtin_bit_cast(uint32_t, f);
  u += 0x7FFFu + ((u >> 16) & 1u);
  return (u16)(u >> 16);
}
__device__ __forceinline__ bf16x8 ldfrag(const u16* p) {
  return __builtin_bit_cast(bf16x8, *(const u16x8*)p);
}
__device__ __forceinline__ void gld16(const void* g, void* l) {
  __builtin_amdgcn_global_load_lds(
      (const __attribute__((address_space(1))) void*)g,
      (__attribute__((address_space(3))) void*)l, 16, 0, 0);
}

// ---------------- weight transpose to bf16: Wt[n][k] = bf16(W[k][n]) -------
__global__ __launch_bounds__(256)
void wtrans(const float* __restrict__ W, int K, int N, u16* __restrict__ Wt) {
  __shared__ float t[32][33];
  int n0 = blockIdx.x * 32, k0 = blockIdx.y * 32;
  int x = threadIdx.x, y = threadIdx.y;  // (32,8)
#pragma unroll
  for (int r = 0; r < 4; r++) t[y + 8*r][x] = W[(size_t)(k0 + y + 8*r) * N + n0 + x];
  __syncthreads();
#pragma unroll
  for (int r = 0; r < 4; r++) Wt[(size_t)(n0 + y + 8*r) * K + k0 + x] = f2bf(t[x][y + 8*r]);
}

__global__ void bcat(const float* __restrict__ bq, const float* __restrict__ bk,
                     const float* __restrict__ bv, float* __restrict__ o) {
  int i = blockIdx.x * 256 + threadIdx.x;
  o[i] = i < 512 ? bq[i] : (i < 1024 ? bk[i - 512] : bv[i - 1024]);
}

// ---------------- layernorm over rows of 512 ------------------------------
// SUM2: x_effective = x + bf16_to_f32(x2)  (split-K combine fused into LN)
template <bool OUT32, bool OUT16, bool SUM2>
__global__ __launch_bounds__(128)
void ln_k(const float* __restrict__ x, const float* __restrict__ g,
          const float* __restrict__ bta, float* __restrict__ y32,
          u16* __restrict__ y16, const u16* __restrict__ x2) {
  int row = blockIdx.x;
  int t = threadIdx.x;
  const float* xr = x + (size_t)row * 512;
  f32x4 v = *(const f32x4*)(xr + t * 4);
  if constexpr (SUM2) {
    u16x4 p2 = *(const u16x4*)(x2 + (size_t)row * 512 + t * 4);
#pragma unroll
    for (int j = 0; j < 4; j++)
      v[j] += __builtin_bit_cast(float, (uint32_t)p2[j] << 16);
  }
  float s = v.x + v.y + v.z + v.w;
  float s2 = v.x*v.x + v.y*v.y + v.z*v.z + v.w*v.w;
#pragma unroll
  for (int m = 32; m; m >>= 1) { s += __shfl_xor(s, m); s2 += __shfl_xor(s2, m); }
  __shared__ float p[4];
  int wv = t >> 6;
  if ((t & 63) == 0) { p[wv] = s; p[2 + wv] = s2; }
  __syncthreads();
  s = p[0] + p[1]; s2 = p[2] + p[3];
  float mean = s * (1.f / 512.f);
  float var = s2 * (1.f / 512.f) - mean * mean;
  float rs = rsqrtf(var + 1e-5f);
#pragma unroll
  for (int j = 0; j < 4; j++) {
    float o = (v[j] - mean) * rs * g[t*4 + j] + bta[t*4 + j];
    if constexpr (OUT32) y32[(size_t)row * 512 + t*4 + j] = o;
    if constexpr (OUT16) y16[(size_t)row * 512 + t*4 + j] = f2bf(o);
  }
}

// ---------------- GEMM: C[M,N] = A[M,K](bf16) @ Wt[N,K]^T + bias ----------
// LDS-staged, double-buffered single-barrier K-loop (r5 structure).
// KSPLIT=2: grid doubles; kh=0 computes K/2 low half -> fp32 + bias + resid,
// kh=1 computes high half -> bf16 partial (combined later in ln_k<SUM2>).
// LDS swizzle: granule c of row r stored at c ^ ((r>>1)&3).
// 1-D grid, XCD-aware raster keeps each A row-stripe in one XCD's L2.
template <int NTW, int NCOL, int KSPLIT, bool RESID, bool OUT32, bool OUT16>
__global__ __launch_bounds__(256)
void gemm_db(const u16* __restrict__ A, const u16* __restrict__ Bt,
             const float* __restrict__ bias, int K, int N,
             const float* __restrict__ resid, float* __restrict__ C32,
             u16* __restrict__ C16) {
  __shared__ __align__(16) u16 As[2][128 * 32];
  __shared__ __align__(16) u16 Bs[2][NTW * 1024];
  const int tid = threadIdx.x;
  const int wave = tid >> 6, lane = tid & 63;
  const int l15 = lane & 15, quad = lane >> 4;
  const int wm = wave >> 1, wn = wave & 1;

  int lin = blockIdx.x;
  int kh = 0;
  if constexpr (KSPLIT == 2) {
    const int nblk = (M_ / 128) * NCOL;
    kh = lin >= nblk;
    lin -= kh * nblk;
  }
  const int rpx = (M_ / 128) / 8;              // row tiles per XCD
  const int xcd = lin & 7, local = lin >> 3;
  const int row0 = (xcd * rpx + local / NCOL) * 128;
  const int col0 = (local % NCOL) * (NTW * 32);
  const int klen = K / KSPLIT;
  const int kstart = kh * klen;

  f32x4 acc[4][NTW];
#pragma unroll
  for (int i = 0; i < 4; i++)
#pragma unroll
    for (int j = 0; j < NTW; j++) acc[i][j] = (f32x4){0.f, 0.f, 0.f, 0.f};

  const int lr = lane >> 2;
  const int lc = ((lane & 3) ^ ((lane >> 3) & 3)) * 8;  // swizzled source granule
  const u16* aG0 = A + (size_t)(row0 + (wave * 2) * 16 + lr) * K + lc;
  const u16* aG1 = A + (size_t)(row0 + (wave * 2 + 1) * 16 + lr) * K + lc;
  const int aO0 = (wave * 2) * 512 + lane * 8;
  const int aO1 = (wave * 2 + 1) * 512 + lane * 8;
  const u16* bG[NTW / 2];
  int bO[NTW / 2];
#pragma unroll
  for (int i = 0; i < NTW / 2; i++) {
    int ch = wave * (NTW / 2) + i;
    bG[i] = Bt + (size_t)(col0 + ch * 16 + lr) * K + lc;
    bO[i] = ch * 512 + lane * 8;
  }
  const int rsw = (l15 >> 1) & 3;  // frag-read swizzle term

  // preload tile 0 into buf 0
  gld16(aG0 + kstart, &As[0][aO0]);
  gld16(aG1 + kstart, &As[0][aO1]);
#pragma unroll
  for (int i = 0; i < NTW / 2; i++) gld16(bG[i] + kstart, &Bs[0][bO[i]]);

  const int nIter = klen >> 5;
  for (int it = 0; it < nIter; it++) {
    __syncthreads();  // drains buf[cur] loads (issued last iter) + prior reads of buf[nxt]
    const int cur = it & 1;
    if (it + 1 < nIter) {
      const int nxt = cur ^ 1;
      const int k = kstart + ((it + 1) << 5);
      gld16(aG0 + k, &As[nxt][aO0]);
      gld16(aG1 + k, &As[nxt][aO1]);
#pragma unroll
      for (int i = 0; i < NTW / 2; i++) gld16(bG[i] + k, &Bs[nxt][bO[i]]);
    }
    bf16x8 af[4], bf[NTW];
#pragma unroll
    for (int mt = 0; mt < 4; mt++)
      af[mt] = ldfrag(&As[cur][(wm * 64 + mt * 16 + l15) * 32 + ((quad ^ rsw) * 8)]);
#pragma unroll
    for (int nt = 0; nt < NTW; nt++)
      bf[nt] = ldfrag(&Bs[cur][(wn * (NTW * 16) + nt * 16 + l15) * 32 + ((quad ^ rsw) * 8)]);
#pragma unroll
    for (int mt = 0; mt < 4; mt++)
#pragma unroll
      for (int nt = 0; nt < NTW; nt++)
        acc[mt][nt] = __builtin_amdgcn_mfma_f32_16x16x32_bf16(af[mt], bf[nt], acc[mt][nt], 0, 0, 0);
  }
#pragma unroll
  for (int mt = 0; mt < 4; mt++)
#pragma unroll
    for (int nt = 0; nt < NTW; nt++) {
      int n = col0 + wn * (NTW * 16) + nt * 16 + l15;
      float bv;
      if constexpr (KSPLIT == 2) bv = (kh == 0) ? bias[n] : 0.f;
      else bv = bias[n];
#pragma unroll
      for (int r = 0; r < 4; r++) {
        int m = row0 + wm * 64 + mt * 16 + quad * 4 + r;
        float val = acc[mt][nt][r] + bv;
        if constexpr (KSPLIT == 2) {
          if (kh == 0) C32[(size_t)m * N + n] = val + resid[(size_t)m * N + n];
          else C16[(size_t)m * N + n] = f2bf(val);
        } else {
          if constexpr (RESID) val += resid[(size_t)m * N + n];
          if constexpr (OUT32) C32[(size_t)m * N + n] = val;
          if constexpr (OUT16) C16[(size_t)m * N + n] = f2bf(val);
        }
      }
    }
}

// ---------------- transpose V head-wise: vt[b,h,d,s] ----------------------
__global__ __launch_bounds__(256)
void vtrans(const u16* __restrict__ qkv, u16* __restrict__ vt) {
  __shared__ u16 t[64][65];
  int s0 = blockIdx.x * 64, h = blockIdx.y, b = blockIdx.z;
  int x = threadIdx.x, y = threadIdx.y;  // (64,4)
  const u16* src = qkv + (size_t)(b * 2048 + s0) * 1536 + 1024 + h * 64;
#pragma unroll
  for (int r = 0; r < 16; r++) { int s = y + 4*r; t[s][x] = src[(size_t)s * 1536 + x]; }
  __syncthreads();
  u16* dst = vt + (size_t)((b * 8 + h) * 64) * 2048 + s0;
#pragma unroll
  for (int r = 0; r < 16; r++) { int d = y + 4*r; dst[(size_t)d * 2048 + x] = t[x][d]; }
}

// ---------------- attention: block = (b, h, 64 q-rows) --------------------
// Grid 1024 1-D, XCD-pinned: all 32 q-blocks of one (b,h) on one XCD.
// Ks: 128x64 u16 (granule c of row r at c^(r&7));  Vts: 64x128 u16
// (granule c at (c&8)|((c&7)^(d&7)));  Ps: 64xPSTR; Qs aliases Ps.
// den computed by MFMA vs all-ones B-frag; P rounded by truncation (bias
// cancels in num/den ratio). Each wave owns its 16 q-rows end-to-end.
#define PSTR 136
__global__ __launch_bounds__(256)
void attn_k(const u16* __restrict__ qkv, const u16* __restrict__ vt,
            const float* __restrict__ hres, float* __restrict__ attn) {
  __shared__ __align__(16) u16 smem[8192 + 8192 + 64 * PSTR];
  u16* Ks = smem;
  u16* Vts = smem + 8192;
  u16* Ps = smem + 16384;
  u16* Qs = Ps;

  const int lin = blockIdx.x;
  const int xcd = lin & 7, g = lin >> 3;
  const int cq = g & 31;               // 64-row q block
  const int bh = xcd * 4 + (g >> 5);   // (b,h) pinned to xcd
  const int hh = bh & 7, b = bh >> 3;
  const int c = cq >> 1;               // 128-chunk index
  const int s0 = cq * 64;
  const int tid = threadIdx.x, wave = tid >> 6, lane = tid & 63;
  const int l15 = lane & 15, quad = lane >> 4;
  const int t_lo = (c > 4) ? c - 4 : 0;
  const int t_hi = (c + 2 < 16) ? c + 2 : 16;
  const int l7sw = l15 & 7;

  // stage Q (64x64), swizzled; each wave stages its own 16 rows
  {
    const int cg = ((lane & 7) ^ (lane >> 3)) * 8;
    const int cp = (lane & 7) * 8;
#pragma unroll
    for (int q2 = 0; q2 < 2; q2++) {
      int r = wave * 16 + q2 * 8 + (lane >> 3);
      gld16(qkv + (size_t)(b * 2048 + s0 + r) * 1536 + hh * 64 + cg, Qs + r * 64 + cp);
    }
  }
  __syncthreads();
  bf16x8 qf[2];
#pragma unroll
  for (int f = 0; f < 2; f++)
    qf[f] = ldfrag(Qs + (wave * 16 + l15) * 64 + (((f * 4 + quad) ^ l7sw) * 8));

  const u16x8 ones16 = {0x3F80, 0x3F80, 0x3F80, 0x3F80, 0x3F80, 0x3F80, 0x3F80, 0x3F80};
  const bf16x8 onesf = __builtin_bit_cast(bf16x8, ones16);

  f32x4 accO[4];
#pragma unroll
  for (int i = 0; i < 4; i++) accO[i] = (f32x4){0.f, 0.f, 0.f, 0.f};
  f32x4 accD = (f32x4){0.f, 0.f, 0.f, 0.f};

  for (int kt = t_lo; kt < t_hi; ++kt) {
    __syncthreads();  // prior-iter reads done before restage
    {
      const int cgk = ((lane & 7) ^ (lane >> 3)) * 8;
      const int cpk = (lane & 7) * 8;
#pragma unroll
      for (int q2 = 0; q2 < 4; q2++) {  // K tile 128 rows
        int r = wave * 32 + q2 * 8 + (lane >> 3);
        gld16(qkv + (size_t)(b * 2048 + kt * 128 + r) * 1536 + 512 + hh * 64 + cgk,
              Ks + r * 64 + cpk);
      }
      const int cpv = (lane & 15) * 8;
#pragma unroll
      for (int q2 = 0; q2 < 4; q2++) {  // Vt tile 64 rows
        int d = (wave * 4 + q2) * 4 + (lane >> 4);
        int cgv = ((lane & 8) | ((lane & 7) ^ (lane >> 4) ^ ((q2 & 1) << 2))) * 8;
        gld16(vt + (size_t)((b * 8 + hh) * 64 + d) * 2048 + kt * 128 + cgv,
              Vts + d * 128 + cpv);
      }
    }
    __syncthreads();

#pragma unroll
    for (int nt = 0; nt < 8; nt++) {
      bf16x8 kf0 = ldfrag(Ks + (nt * 16 + l15) * 64 + ((quad ^ l7sw) * 8));
      bf16x8 kf1 = ldfrag(Ks + (nt * 16 + l15) * 64 + (((4 + quad) ^ l7sw) * 8));
      f32x4 s4 = (f32x4){0.f, 0.f, 0.f, 0.f};
      s4 = __builtin_amdgcn_mfma_f32_16x16x32_bf16(qf[0], kf0, s4, 0, 0, 0);
      s4 = __builtin_amdgcn_mfma_f32_16x16x32_bf16(qf[1], kf1, s4, 0, 0, 0);
#pragma unroll
      for (int r = 0; r < 4; r++) {
        float pp = exp2f(s4[r] * (1.4426950408889634f * 0.125f));  // exp(s/8)
        Ps[(wave * 16 + quad * 4 + r) * PSTR + nt * 16 + l15] =
            (u16)(__builtin_bit_cast(uint32_t, pp) >> 16);  // truncate
      }
    }
    // PV — wave reads only its own P rows, no cross-wave barrier needed
#pragma unroll
    for (int ki = 0; ki < 4; ki++) {
      bf16x8 pf = ldfrag(Ps + (wave * 16 + l15) * PSTR + (ki * 4 + quad) * 8);
      accD = __builtin_amdgcn_mfma_f32_16x16x32_bf16(pf, onesf, accD, 0, 0, 0);
#pragma unroll
      for (int dt = 0; dt < 4; dt++) {
        int gg = ki * 4 + quad;
        bf16x8 vf = ldfrag(Vts + (dt * 16 + l15) * 128 + (((gg & 8) | ((gg & 7) ^ l7sw)) * 8));
        accO[dt] = __builtin_amdgcn_mfma_f32_16x16x32_bf16(pf, vf, accO[dt], 0, 0, 0);
      }
    }
  }
#pragma unroll
  for (int r = 0; r < 4; r++) {
    float dinv = 1.0f / accD[r];
    int m = s0 + wave * 16 + quad * 4 + r;
#pragma unroll
    for (int dt = 0; dt < 4; dt++) {
      size_t idx = (size_t)(b * 2048 + m) * 512 + hh * 64 + dt * 16 + l15;
      attn[idx] = accO[dt][r] * dinv + hres[idx];
    }
  }
}

extern "C" void kernel_launch(void* const* d_in, const int* in_sizes, int n_in,
                              void* d_out, int out_size, void* d_ws, size_t ws_size,
                              hipStream_t stream) {
  (void)in_sizes; (void)n_in; (void)out_size; (void)ws_size;
  const float* x       = (const float*)d_in[0];
  const float* ln_in_g = (const float*)d_in[2];
  const float* ln_in_b = (const float*)d_in[3];
  const float* wq = (const float*)d_in[4];
  const float* bq = (const float*)d_in[5];
  const float* wk = (const float*)d_in[6];
  const float* bk = (const float*)d_in[7];
  const float* wv = (const float*)d_in[8];
  const float* bv = (const float*)d_in[9];
  const float* ln1_g = (const float*)d_in[10];
  const float* ln1_b = (const float*)d_in[11];
  const float* w1 = (const float*)d_in[12];
  const float* b1 = (const float*)d_in[13];
  const float* w2 = (const float*)d_in[14];
  const float* b2 = (const float*)d_in[15];
  const float* ln2_g = (const float*)d_in[16];
  const float* ln2_b = (const float*)d_in[17];

  char* ws = (char*)d_ws;
  size_t off = 0;
  auto alloc = [&](size_t bytes) {
    void* p = ws + off;
    off = (off + bytes + 255) & ~(size_t)255;
    return p;
  };
  u16*   wqkvt = (u16*)  alloc((size_t)1536 * 512 * 2);
  float* bqkv  = (float*)alloc(1536 * 4);
  u16*   w1t   = (u16*)  alloc((size_t)2048 * 512 * 2);
  u16*   w2t   = (u16*)  alloc((size_t)512 * 2048 * 2);
  float* h32   = (float*)alloc((size_t)M_ * 512 * 4);   // later reused as out2
  u16*   h16   = (u16*)  alloc((size_t)M_ * 512 * 2);   // later: FFN2 kh1 partial
  u16*   qkv16 = (u16*)  alloc((size_t)M_ * 1536 * 2);  // + vt below = ffn-mid alias
  u16*   vtb   = (u16*)  alloc((size_t)B_ * H_ * 64 * 2048 * 2);
  float* attn32= (float*)alloc((size_t)M_ * 512 * 4);
  float* out2  = h32;
  u16*   o16   = h16;
  u16*   f16b  = qkv16;  // 8192*2048*2 bytes spans qkv16+vtb exactly

  wtrans<<<dim3(16, 16), dim3(32, 8), 0, stream>>>(wq, 512, 512, wqkvt);
  wtrans<<<dim3(16, 16), dim3(32, 8), 0, stream>>>(wk, 512, 512, wqkvt + (size_t)512 * 512);
  wtrans<<<dim3(16, 16), dim3(32, 8), 0, stream>>>(wv, 512, 512, wqkvt + (size_t)1024 * 512);
  wtrans<<<dim3(64, 16), dim3(32, 8), 0, stream>>>(w1, 512, 2048, w1t);
  wtrans<<<dim3(16, 64), dim3(32, 8), 0, stream>>>(w2, 2048, 512, w2t);
  bcat<<<6, 256, 0, stream>>>(bq, bk, bv, bqkv);

  ln_k<true, true, false><<<M_, 128, 0, stream>>>(x, ln_in_g, ln_in_b, h32, h16, nullptr);
  gemm_db<4, 12, 1, false, false, true><<<dim3(12 * 64), 256, 0, stream>>>(
      h16, wqkvt, bqkv, 512, 1536, nullptr, nullptr, qkv16);
  vtrans<<<dim3(32, 8, 4), dim3(64, 4), 0, stream>>>(qkv16, vtb);
  attn_k<<<dim3(1024), 256, 0, stream>>>(qkv16, vtb, h32, attn32);
  ln_k<false, true, false><<<M_, 128, 0, stream>>>(attn32, ln1_g, ln1_b, nullptr, o16, nullptr);
  gemm_db<4, 16, 1, false, false, true><<<dim3(16 * 64), 256, 0, stream>>>(
      o16, w1t, b1, 512, 2048, nullptr, nullptr, f16b);
  gemm_db<2, 8, 2, false, false, false><<<dim3(2 * 8 * 64), 256, 0, stream>>>(
      f16b, w2t, b2, 2048, 512, attn32, out2, h16);
  ln_k<true, false, true><<<M_, 128, 0, stream>>>(out2, ln2_g, ln2_b, (float*)d_out, nullptr, h16);
}

// Round 7
// 293.499 us; speedup vs baseline: 1.3977x; 1.0091x over previous
//
#include <hip/hip_runtime.h>
#include <stdint.h>

#define B_ 4
#define S_ 2048
#define D_ 512
#define H_ 8
#define FFN_ 2048
#define M_ (B_*S_)

typedef unsigned short u16;
typedef __attribute__((ext_vector_type(8))) __bf16 bf16x8;
typedef __attribute__((ext_vector_type(8))) u16 u16x8;
typedef __attribute__((ext_vector_type(4))) u16 u16x4;
typedef __attribute__((ext_vector_type(4))) float f32x4;

__device__ __forceinline__ u16 f2bf(float f) {
  uint32_t u = __builtin_bit_cast(uint32_t, f);
  u += 0x7FFFu + ((u >> 16) & 1u);
  return (u16)(u >> 16);
}
__device__ __forceinline__ bf16x8 ldfrag(const u16* p) {
  return __builtin_bit_cast(bf16x8, *(const u16x8*)p);
}
__device__ __forceinline__ void gld16(const void* g, void* l) {
  __builtin_amdgcn_global_load_lds(
      (const __attribute__((address_space(1))) void*)g,
      (__attribute__((address_space(3))) void*)l, 16, 0, 0);
}
// raw barrier with partial vmcnt wait: keeps prefetch loads in flight across
// the barrier (the __syncthreads vmcnt(0) drain is the structural stall).
// Safe: by barrier-crossing every wave's ds_reads are already consumed
// (compiler lgkmcnt waits precede the MFMAs that use them).
template <int N>
__device__ __forceinline__ void wait_vm_barrier() {
  if constexpr (N == 0)      asm volatile("s_waitcnt vmcnt(0)\n\ts_barrier" ::: "memory");
  else if constexpr (N == 3) asm volatile("s_waitcnt vmcnt(3)\n\ts_barrier" ::: "memory");
  else if constexpr (N == 4) asm volatile("s_waitcnt vmcnt(4)\n\ts_barrier" ::: "memory");
  else if constexpr (N == 8) asm volatile("s_waitcnt vmcnt(8)\n\ts_barrier" ::: "memory");
}
__device__ __forceinline__ void barrier_only() {
  asm volatile("s_barrier" ::: "memory");
}

// ---------------- weight transpose to bf16: Wt[n][k] = bf16(W[k][n]) -------
__global__ __launch_bounds__(256)
void wtrans(const float* __restrict__ W, int K, int N, u16* __restrict__ Wt) {
  __shared__ float t[32][33];
  int n0 = blockIdx.x * 32, k0 = blockIdx.y * 32;
  int x = threadIdx.x, y = threadIdx.y;  // (32,8)
#pragma unroll
  for (int r = 0; r < 4; r++) t[y + 8*r][x] = W[(size_t)(k0 + y + 8*r) * N + n0 + x];
  __syncthreads();
#pragma unroll
  for (int r = 0; r < 4; r++) Wt[(size_t)(n0 + y + 8*r) * K + k0 + x] = f2bf(t[x][y + 8*r]);
}

// 3 square 512x512 transposes in one launch (z selects q/k/v)
__global__ __launch_bounds__(256)
void wtrans3(const float* __restrict__ Wq, const float* __restrict__ Wk,
             const float* __restrict__ Wv, u16* __restrict__ Wt) {
  __shared__ float t[32][33];
  int z = blockIdx.z;
  const float* W = z == 0 ? Wq : (z == 1 ? Wk : Wv);
  u16* dst = Wt + (size_t)z * 512 * 512;
  int n0 = blockIdx.x * 32, k0 = blockIdx.y * 32;
  int x = threadIdx.x, y = threadIdx.y;  // (32,8)
#pragma unroll
  for (int r = 0; r < 4; r++) t[y + 8*r][x] = W[(size_t)(k0 + y + 8*r) * 512 + n0 + x];
  __syncthreads();
#pragma unroll
  for (int r = 0; r < 4; r++) dst[(size_t)(n0 + y + 8*r) * 512 + k0 + x] = f2bf(t[x][y + 8*r]);
}

__global__ void bcat(const float* __restrict__ bq, const float* __restrict__ bk,
                     const float* __restrict__ bv, float* __restrict__ o) {
  int i = blockIdx.x * 256 + threadIdx.x;
  o[i] = i < 512 ? bq[i] : (i < 1024 ? bk[i - 512] : bv[i - 1024]);
}

// ---------------- layernorm over rows of 512 ------------------------------
// SUM2: x_effective = x + bf16_to_f32(x2)  (split-K combine fused into LN)
template <bool OUT32, bool OUT16, bool SUM2>
__global__ __launch_bounds__(128)
void ln_k(const float* __restrict__ x, const float* __restrict__ g,
          const float* __restrict__ bta, float* __restrict__ y32,
          u16* __restrict__ y16, const u16* __restrict__ x2) {
  int row = blockIdx.x;
  int t = threadIdx.x;
  const float* xr = x + (size_t)row * 512;
  f32x4 v = *(const f32x4*)(xr + t * 4);
  if constexpr (SUM2) {
    u16x4 p2 = *(const u16x4*)(x2 + (size_t)row * 512 + t * 4);
#pragma unroll
    for (int j = 0; j < 4; j++)
      v[j] += __builtin_bit_cast(float, (uint32_t)p2[j] << 16);
  }
  float s = v.x + v.y + v.z + v.w;
  float s2 = v.x*v.x + v.y*v.y + v.z*v.z + v.w*v.w;
#pragma unroll
  for (int m = 32; m; m >>= 1) { s += __shfl_xor(s, m); s2 += __shfl_xor(s2, m); }
  __shared__ float p[4];
  int wv = t >> 6;
  if ((t & 63) == 0) { p[wv] = s; p[2 + wv] = s2; }
  __syncthreads();
  s = p[0] + p[1]; s2 = p[2] + p[3];
  float mean = s * (1.f / 512.f);
  float var = s2 * (1.f / 512.f) - mean * mean;
  float rs = rsqrtf(var + 1e-5f);
#pragma unroll
  for (int j = 0; j < 4; j++) {
    float o = (v[j] - mean) * rs * g[t*4 + j] + bta[t*4 + j];
    if constexpr (OUT32) y32[(size_t)row * 512 + t*4 + j] = o;
    if constexpr (OUT16) y16[(size_t)row * 512 + t*4 + j] = f2bf(o);
  }
}

// ---------------- GEMM: C[M,N] = A[M,K](bf16) @ Wt[N,K]^T + bias ----------
// 3-buffer LDS pipeline, ONE raw barrier per K-iter with vmcnt(L) (not 0):
// iter i waits only for loads issued at iter i-2/i-1's prefetch, while the
// next tile's loads stay in flight across the barrier (AITER pattern).
// LDS swizzle: granule c of row r stored at c ^ ((r>>1)&3).
// 1-D grid, XCD-aware raster keeps each A row-stripe in one XCD's L2.
template <int NTW, int NCOL, int KSPLIT, bool RESID, bool OUT32, bool OUT16>
__global__ __launch_bounds__(256)
void gemm_db(const u16* __restrict__ A, const u16* __restrict__ Bt,
             const float* __restrict__ bias, int K, int N,
             const float* __restrict__ resid, float* __restrict__ C32,
             u16* __restrict__ C16) {
  __shared__ __align__(16) u16 As[3][128 * 32];
  __shared__ __align__(16) u16 Bs[3][NTW * 1024];
  const int tid = threadIdx.x;
  const int wave = tid >> 6, lane = tid & 63;
  const int l15 = lane & 15, quad = lane >> 4;
  const int wm = wave >> 1, wn = wave & 1;

  int lin = blockIdx.x;
  int kh = 0;
  if constexpr (KSPLIT == 2) {
    const int nblk = (M_ / 128) * NCOL;
    kh = lin >= nblk;
    lin -= kh * nblk;
  }
  const int rpx = (M_ / 128) / 8;              // row tiles per XCD
  const int xcd = lin & 7, local = lin >> 3;
  const int row0 = (xcd * rpx + local / NCOL) * 128;
  const int col0 = (local % NCOL) * (NTW * 32);
  const int klen = K / KSPLIT;
  const int kstart = kh * klen;

  f32x4 acc[4][NTW];
#pragma unroll
  for (int i = 0; i < 4; i++)
#pragma unroll
    for (int j = 0; j < NTW; j++) acc[i][j] = (f32x4){0.f, 0.f, 0.f, 0.f};

  const int lr = lane >> 2;
  const int lc = ((lane & 3) ^ ((lane >> 3) & 3)) * 8;  // swizzled source granule
  const u16* aG0 = A + (size_t)(row0 + (wave * 2) * 16 + lr) * K + lc;
  const u16* aG1 = A + (size_t)(row0 + (wave * 2 + 1) * 16 + lr) * K + lc;
  const int aO0 = (wave * 2) * 512 + lane * 8;
  const int aO1 = (wave * 2 + 1) * 512 + lane * 8;
  const u16* bG[NTW / 2];
  int bO[NTW / 2];
#pragma unroll
  for (int i = 0; i < NTW / 2; i++) {
    int ch = wave * (NTW / 2) + i;
    bG[i] = Bt + (size_t)(col0 + ch * 16 + lr) * K + lc;
    bO[i] = ch * 512 + lane * 8;
  }
  const int rsw = (l15 >> 1) & 3;  // frag-read swizzle term
  constexpr int L = 2 + NTW / 2;   // vmem loads per iter per lane

  auto issue = [&](int kof, int buf) {
    gld16(aG0 + kof, &As[buf][aO0]);
    gld16(aG1 + kof, &As[buf][aO1]);
#pragma unroll
    for (int i = 0; i < NTW / 2; i++) gld16(bG[i] + kof, &Bs[buf][bO[i]]);
  };

  const int nIter = klen >> 5;
  issue(kstart, 0);
  issue(kstart + 32, 1);  // nIter >= 16 always

  int cur = 0;
  for (int it = 0; it < nIter; it++) {
    if (it + 1 < nIter) wait_vm_barrier<L>();   // drains iter-it loads only
    else wait_vm_barrier<0>();
    int pf = cur + 2; if (pf >= 3) pf -= 3;
    if (it + 2 < nIter) issue(kstart + ((it + 2) << 5), pf);
    bf16x8 af[4], bf[NTW];
#pragma unroll
    for (int mt = 0; mt < 4; mt++)
      af[mt] = ldfrag(&As[cur][(wm * 64 + mt * 16 + l15) * 32 + ((quad ^ rsw) * 8)]);
#pragma unroll
    for (int nt = 0; nt < NTW; nt++)
      bf[nt] = ldfrag(&Bs[cur][(wn * (NTW * 16) + nt * 16 + l15) * 32 + ((quad ^ rsw) * 8)]);
#pragma unroll
    for (int mt = 0; mt < 4; mt++)
#pragma unroll
      for (int nt = 0; nt < NTW; nt++)
        acc[mt][nt] = __builtin_amdgcn_mfma_f32_16x16x32_bf16(af[mt], bf[nt], acc[mt][nt], 0, 0, 0);
    cur = cur == 2 ? 0 : cur + 1;
  }
#pragma unroll
  for (int mt = 0; mt < 4; mt++)
#pragma unroll
    for (int nt = 0; nt < NTW; nt++) {
      int n = col0 + wn * (NTW * 16) + nt * 16 + l15;
      float bv;
      if constexpr (KSPLIT == 2) bv = (kh == 0) ? bias[n] : 0.f;
      else bv = bias[n];
#pragma unroll
      for (int r = 0; r < 4; r++) {
        int m = row0 + wm * 64 + mt * 16 + quad * 4 + r;
        float val = acc[mt][nt][r] + bv;
        if constexpr (KSPLIT == 2) {
          if (kh == 0) C32[(size_t)m * N + n] = val + resid[(size_t)m * N + n];
          else C16[(size_t)m * N + n] = f2bf(val);
        } else {
          if constexpr (RESID) val += resid[(size_t)m * N + n];
          if constexpr (OUT32) C32[(size_t)m * N + n] = val;
          if constexpr (OUT16) C16[(size_t)m * N + n] = f2bf(val);
        }
      }
    }
}

// ---------------- transpose V head-wise: vt[b,h,d,s] ----------------------
__global__ __launch_bounds__(256)
void vtrans(const u16* __restrict__ qkv, u16* __restrict__ vt) {
  __shared__ u16 t[64][65];
  int s0 = blockIdx.x * 64, h = blockIdx.y, b = blockIdx.z;
  int x = threadIdx.x, y = threadIdx.y;  // (64,4)
  const u16* src = qkv + (size_t)(b * 2048 + s0) * 1536 + 1024 + h * 64;
#pragma unroll
  for (int r = 0; r < 16; r++) { int s = y + 4*r; t[s][x] = src[(size_t)s * 1536 + x]; }
  __syncthreads();
  u16* dst = vt + (size_t)((b * 8 + h) * 64) * 2048 + s0;
#pragma unroll
  for (int r = 0; r < 16; r++) { int d = y + 4*r; dst[(size_t)d * 2048 + x] = t[x][d]; }
}

// ---------------- attention: block = (b, h, 64 q-rows) --------------------
// Grid 1024 1-D, XCD-pinned. Depth-2 pipelined K/V staging with raw
// barriers + vmcnt(8) (loads for tile kt+1 stay in flight while computing
// tile kt). Ks: 2x 128x64 u16 (granule c of row r at c^(r&7)); Vts: 2x
// 64x128 (granule c at (c&8)|((c&7)^(d&7))); Ps: 64x128 u16, granule-XOR
// swizzle (phys granule = logical ^ (row&15)) -> 80 KB total, 2 blocks/CU.
// den via MFMA vs all-ones frag; P rounded by truncation (cancels in ratio).
__global__ __launch_bounds__(256)
void attn_k(const u16* __restrict__ qkv, const u16* __restrict__ vt,
            const float* __restrict__ hres, float* __restrict__ attn) {
  __shared__ __align__(16) u16 smem[2 * 8192 + 2 * 8192 + 64 * 128];
  u16* Ks = smem;            // [2][8192]
  u16* Vts = smem + 16384;   // [2][8192]
  u16* Ps = smem + 32768;    // [64*128]
  u16* Qs = Ps;

  const int lin = blockIdx.x;
  const int xcd = lin & 7, g = lin >> 3;
  const int cq = g & 31;               // 64-row q block
  const int bh = xcd * 4 + (g >> 5);   // (b,h) pinned to xcd
  const int hh = bh & 7, b = bh >> 3;
  const int c = cq >> 1;               // 128-chunk index
  const int s0 = cq * 64;
  const int tid = threadIdx.x, wave = tid >> 6, lane = tid & 63;
  const int l15 = lane & 15, quad = lane >> 4;
  const int t_lo = (c > 4) ? c - 4 : 0;
  const int t_hi = (c + 2 < 16) ? c + 2 : 16;
  const int l7sw = l15 & 7;

  const int cgk = ((lane & 7) ^ (lane >> 3)) * 8;
  const int cpk = (lane & 7) * 8;
  const int cpv = (lane & 15) * 8;

  auto issueKV = [&](int kt, int buf) {
#pragma unroll
    for (int q2 = 0; q2 < 4; q2++) {  // K tile 128 rows
      int r = wave * 32 + q2 * 8 + (lane >> 3);
      gld16(qkv + (size_t)(b * 2048 + kt * 128 + r) * 1536 + 512 + hh * 64 + cgk,
            Ks + buf * 8192 + r * 64 + cpk);
    }
#pragma unroll
    for (int q2 = 0; q2 < 4; q2++) {  // Vt tile 64 rows
      int d = (wave * 4 + q2) * 4 + (lane >> 4);
      int cgv = ((lane & 8) | ((lane & 7) ^ (lane >> 4) ^ ((q2 & 1) << 2))) * 8;
      gld16(vt + (size_t)((b * 8 + hh) * 64 + d) * 2048 + kt * 128 + cgv,
            Vts + buf * 8192 + d * 128 + cpv);
    }
  };

  // stage Q (64x64), swizzled; plus first K/V tile
  {
#pragma unroll
    for (int q2 = 0; q2 < 2; q2++) {
      int r = wave * 16 + q2 * 8 + (lane >> 3);
      gld16(qkv + (size_t)(b * 2048 + s0 + r) * 1536 + hh * 64 + cgk, Qs + r * 64 + cpk);
    }
  }
  issueKV(t_lo, 0);
  __syncthreads();  // drains Q + first K/V
  bf16x8 qf[2];
#pragma unroll
  for (int f = 0; f < 2; f++)
    qf[f] = ldfrag(Qs + (wave * 16 + l15) * 64 + (((f * 4 + quad) ^ l7sw) * 8));

  const u16x8 ones16 = {0x3F80, 0x3F80, 0x3F80, 0x3F80, 0x3F80, 0x3F80, 0x3F80, 0x3F80};
  const bf16x8 onesf = __builtin_bit_cast(bf16x8, ones16);

  f32x4 accO[4];
#pragma unroll
  for (int i = 0; i < 4; i++) accO[i] = (f32x4){0.f, 0.f, 0.f, 0.f};
  f32x4 accD = (f32x4){0.f, 0.f, 0.f, 0.f};

  for (int kt = t_lo; kt < t_hi; ++kt) {
    const int j = kt - t_lo, cur = j & 1, nxt = cur ^ 1;
    barrier_only();  // all waves done reading buf[nxt] (prev iter)
    if (kt + 1 < t_hi) {
      issueKV(kt + 1, nxt);
      wait_vm_barrier<8>();  // drains tile-kt loads; kt+1 stays in flight
    } else {
      wait_vm_barrier<0>();
    }
    const u16* Kc = Ks + cur * 8192;
    const u16* Vc = Vts + cur * 8192;

#pragma unroll
    for (int nt = 0; nt < 8; nt++) {
      bf16x8 kf0 = ldfrag(Kc + (nt * 16 + l15) * 64 + ((quad ^ l7sw) * 8));
      bf16x8 kf1 = ldfrag(Kc + (nt * 16 + l15) * 64 + (((4 + quad) ^ l7sw) * 8));
      f32x4 s4 = (f32x4){0.f, 0.f, 0.f, 0.f};
      s4 = __builtin_amdgcn_mfma_f32_16x16x32_bf16(qf[0], kf0, s4, 0, 0, 0);
      s4 = __builtin_amdgcn_mfma_f32_16x16x32_bf16(qf[1], kf1, s4, 0, 0, 0);
#pragma unroll
      for (int r = 0; r < 4; r++) {
        float pp = exp2f(s4[r] * (1.4426950408889634f * 0.125f));  // exp(s/8)
        Ps[(wave * 16 + quad * 4 + r) * 128 +
           (((nt * 2 + (l15 >> 3)) ^ (quad * 4 + r)) * 8) + (l15 & 7)] =
            (u16)(__builtin_bit_cast(uint32_t, pp) >> 16);  // truncate
      }
    }
    // PV — wave reads only its own P rows, no cross-wave barrier needed
#pragma unroll
    for (int ki = 0; ki < 4; ki++) {
      bf16x8 pf = ldfrag(Ps + (wave * 16 + l15) * 128 + (((ki * 4 + quad) ^ l15) * 8));
      accD = __builtin_amdgcn_mfma_f32_16x16x32_bf16(pf, onesf, accD, 0, 0, 0);
#pragma unroll
      for (int dt = 0; dt < 4; dt++) {
        int gg = ki * 4 + quad;
        bf16x8 vf = ldfrag(Vc + (dt * 16 + l15) * 128 + (((gg & 8) | ((gg & 7) ^ l7sw)) * 8));
        accO[dt] = __builtin_amdgcn_mfma_f32_16x16x32_bf16(pf, vf, accO[dt], 0, 0, 0);
      }
    }
  }
#pragma unroll
  for (int r = 0; r < 4; r++) {
    float dinv = 1.0f / accD[r];
    int m = s0 + wave * 16 + quad * 4 + r;
#pragma unroll
    for (int dt = 0; dt < 4; dt++) {
      size_t idx = (size_t)(b * 2048 + m) * 512 + hh * 64 + dt * 16 + l15;
      attn[idx] = accO[dt][r] * dinv + hres[idx];
    }
  }
}

extern "C" void kernel_launch(void* const* d_in, const int* in_sizes, int n_in,
                              void* d_out, int out_size, void* d_ws, size_t ws_size,
                              hipStream_t stream) {
  (void)in_sizes; (void)n_in; (void)out_size; (void)ws_size;
  const float* x       = (const float*)d_in[0];
  const float* ln_in_g = (const float*)d_in[2];
  const float* ln_in_b = (const float*)d_in[3];
  const float* wq = (const float*)d_in[4];
  const float* bq = (const float*)d_in[5];
  const float* wk = (const float*)d_in[6];
  const float* bk = (const float*)d_in[7];
  const float* wv = (const float*)d_in[8];
  const float* bv = (const float*)d_in[9];
  const float* ln1_g = (const float*)d_in[10];
  const float* ln1_b = (const float*)d_in[11];
  const float* w1 = (const float*)d_in[12];
  const float* b1 = (const float*)d_in[13];
  const float* w2 = (const float*)d_in[14];
  const float* b2 = (const float*)d_in[15];
  const float* ln2_g = (const float*)d_in[16];
  const float* ln2_b = (const float*)d_in[17];

  char* ws = (char*)d_ws;
  size_t off = 0;
  auto alloc = [&](size_t bytes) {
    void* p = ws + off;
    off = (off + bytes + 255) & ~(size_t)255;
    return p;
  };
  u16*   wqkvt = (u16*)  alloc((size_t)1536 * 512 * 2);
  float* bqkv  = (float*)alloc(1536 * 4);
  u16*   w1t   = (u16*)  alloc((size_t)2048 * 512 * 2);
  u16*   w2t   = (u16*)  alloc((size_t)512 * 2048 * 2);
  float* h32   = (float*)alloc((size_t)M_ * 512 * 4);   // later reused as out2
  u16*   h16   = (u16*)  alloc((size_t)M_ * 512 * 2);   // later: FFN2 kh1 partial
  u16*   qkv16 = (u16*)  alloc((size_t)M_ * 1536 * 2);  // + vt below = ffn-mid alias
  u16*   vtb   = (u16*)  alloc((size_t)B_ * H_ * 64 * 2048 * 2);
  float* attn32= (float*)alloc((size_t)M_ * 512 * 4);
  float* out2  = h32;
  u16*   o16   = h16;
  u16*   f16b  = qkv16;  // 8192*2048*2 bytes spans qkv16+vtb exactly

  wtrans3<<<dim3(16, 16, 3), dim3(32, 8), 0, stream>>>(wq, wk, wv, wqkvt);
  wtrans<<<dim3(64, 16), dim3(32, 8), 0, stream>>>(w1, 512, 2048, w1t);
  wtrans<<<dim3(16, 64), dim3(32, 8), 0, stream>>>(w2, 2048, 512, w2t);
  bcat<<<6, 256, 0, stream>>>(bq, bk, bv, bqkv);

  ln_k<true, true, false><<<M_, 128, 0, stream>>>(x, ln_in_g, ln_in_b, h32, h16, nullptr);
  gemm_db<4, 12, 1, false, false, true><<<dim3(12 * 64), 256, 0, stream>>>(
      h16, wqkvt, bqkv, 512, 1536, nullptr, nullptr, qkv16);
  vtrans<<<dim3(32, 8, 4), dim3(64, 4), 0, stream>>>(qkv16, vtb);
  attn_k<<<dim3(1024), 256, 0, stream>>>(qkv16, vtb, h32, attn32);
  ln_k<false, true, false><<<M_, 128, 0, stream>>>(attn32, ln1_g, ln1_b, nullptr, o16, nullptr);
  gemm_db<2, 32, 1, false, false, true><<<dim3(32 * 64), 256, 0, stream>>>(
      o16, w1t, b1, 512, 2048, nullptr, nullptr, f16b);
  gemm_db<2, 8, 2, false, false, false><<<dim3(2 * 8 * 64), 256, 0, stream>>>(
      f16b, w2t, b2, 2048, 512, attn32, out2, h16);
  ln_k<true, false, true><<<M_, 128, 0, stream>>>(out2, ln2_g, ln2_b, (float*)d_out, nullptr, h16);
}